// Round 7
// baseline (2040.303 us; speedup 1.0000x reference)
//
#include <hip/hip_runtime.h>
#include <stdint.h>

#define T_SEQ 256
#define NB    8
#define EMB   512
#define HID   1024
#define NOUT  32000

typedef float    f32x4  __attribute__((ext_vector_type(4)));
typedef unsigned int u32x4 __attribute__((ext_vector_type(4)));
typedef __bf16   bf16x8 __attribute__((ext_vector_type(8)));

#define AS1 __attribute__((address_space(1)))
#define AS3 __attribute__((address_space(3)))

__device__ __forceinline__ uint32_t f2bf(float f) {
    uint32_t u = __builtin_bit_cast(uint32_t, f);
    u += 0x7FFFu + ((u >> 16) & 1u);   // RNE
    return (u >> 16);
}

__device__ __forceinline__ bf16x8 mk_hi(u32x4 a, u32x4 b) {
    u32x4 r;
    r.x = __builtin_amdgcn_perm(a.y, a.x, 0x07060302u);
    r.y = __builtin_amdgcn_perm(a.w, a.z, 0x07060302u);
    r.z = __builtin_amdgcn_perm(b.y, b.x, 0x07060302u);
    r.w = __builtin_amdgcn_perm(b.w, b.z, 0x07060302u);
    return __builtin_bit_cast(bf16x8, r);
}
__device__ __forceinline__ bf16x8 mk_lo(u32x4 a, u32x4 b) {
    u32x4 r;
    r.x = __builtin_amdgcn_perm(a.y, a.x, 0x05040100u);
    r.y = __builtin_amdgcn_perm(a.w, a.z, 0x05040100u);
    r.z = __builtin_amdgcn_perm(b.y, b.x, 0x05040100u);
    r.w = __builtin_amdgcn_perm(b.w, b.z, 0x05040100u);
    return __builtin_bit_cast(bf16x8, r);
}

// ---------------- W_fc fp32 -> bf16 ----------------
__global__ void k_convert_wfc(const float* __restrict__ src, unsigned short* __restrict__ dst) {
    int i = blockIdx.x * blockDim.x + threadIdx.x;
    const f32x4* s4 = (const f32x4*)src;
    int n4 = NOUT * HID / 4;
    int stride = gridDim.x * blockDim.x;
    for (int idx = i; idx < n4; idx += stride) {
        f32x4 v = s4[idx];
        uint2 o;
        o.x = f2bf(v.x) | (f2bf(v.y) << 16);
        o.y = f2bf(v.z) | (f2bf(v.w) << 16);
        ((uint2*)dst)[idx] = o;
    }
}

// ---------------- embed gather + xproj = emb @ W_ih^T + b_ih (fp32) ----------------
__global__ __launch_bounds__(256) void k_xproj(
        const int* __restrict__ inputs, const float* __restrict__ embed,
        const float* __restrict__ W_ih, const float* __restrict__ b_ih,
        float* __restrict__ xproj) {
    __shared__ float As[64][33];
    __shared__ float Bs[64][33];
    __shared__ int   idx_s[64];
    const int tid = threadIdx.x;
    const int bm = blockIdx.y, bn = blockIdx.x;
    if (tid < 64) {
        int m = bm * 64 + tid;
        idx_s[tid] = inputs[(m & 7) * T_SEQ + (m >> 3)];
    }
    __syncthreads();
    const int ty = tid >> 4, tx = tid & 15;
    const int lr = tid >> 2, lc = (tid & 3) * 8;
    float acc[4][4] = {};
    for (int kk = 0; kk < EMB; kk += 32) {
        __syncthreads();
        const float* arow = embed + (size_t)idx_s[lr] * EMB + kk + lc;
        f32x4 a0 = *(const f32x4*)arow;
        f32x4 a1 = *(const f32x4*)(arow + 4);
        const float* brow = W_ih + (size_t)(bn * 64 + lr) * EMB + kk + lc;
        f32x4 b0 = *(const f32x4*)brow;
        f32x4 b1 = *(const f32x4*)(brow + 4);
#pragma unroll
        for (int u = 0; u < 4; ++u) {
            As[lr][lc + u] = a0[u]; As[lr][lc + 4 + u] = a1[u];
            Bs[lr][lc + u] = b0[u]; Bs[lr][lc + 4 + u] = b1[u];
        }
        __syncthreads();
#pragma unroll
        for (int k = 0; k < 32; ++k) {
            float av[4], bv[4];
#pragma unroll
            for (int i = 0; i < 4; ++i) av[i] = As[ty * 4 + i][k];
#pragma unroll
            for (int j = 0; j < 4; ++j) bv[j] = Bs[tx * 4 + j][k];
#pragma unroll
            for (int i = 0; i < 4; ++i)
#pragma unroll
                for (int j = 0; j < 4; ++j) acc[i][j] += av[i] * bv[j];
        }
    }
#pragma unroll
    for (int i = 0; i < 4; ++i) {
        int m = bm * 64 + ty * 4 + i;
#pragma unroll
        for (int j = 0; j < 4; ++j) {
            int n = bn * 64 + tx * 4 + j;
            xproj[(size_t)m * HID + n] = acc[i][j] + b_ih[n];
        }
    }
}

// ---------------- persistent recurrence: 64 blocks x 256 threads, MFMA ----------------
// Flags (bypass, 256 B/iter) gate bulk CACHED h loads from a never-reused
// per-step slot array hseq[256][8][1024]. Producers: sc0sc1 data stores ->
// vmcnt(0) -> atomic flag. Split-bf16 3-MFMA compute (fp32-equivalent).
#define RBLK 64
__global__ __launch_bounds__(256, 1) void k_rnn(
        const float* __restrict__ W_hh, const float* __restrict__ b_hh,
        const float* __restrict__ xproj,
        unsigned int* __restrict__ hseq /* [256][8][1024] u32 */,
        unsigned short* __restrict__ hs /* [2048][1024] bf16 */,
        unsigned int* __restrict__ prog /* [64] */) {
    __shared__ __align__(16) float part[2][4][64][4];   // 8 KB, dbuf by t&1
    const int tid = threadIdx.x;
    const int w   = tid >> 6;
    const int ln  = tid & 63;
    const int blk = blockIdx.x;

    const float* wrow = W_hh + (size_t)(blk * 16 + (ln & 15)) * HID;
    bf16x8 whi[8], wlo[8];
#pragma unroll
    for (int cc = 0; cc < 8; ++cc) {
        int k0 = w * 256 + cc * 32 + (ln >> 4) * 8;
        f32x4 wa = *(const f32x4*)(wrow + k0);
        f32x4 wb = *(const f32x4*)(wrow + k0 + 4);
        float wv[8] = { wa.x, wa.y, wa.z, wa.w, wb.x, wb.y, wb.z, wb.w };
        uint32_t hu[8], lu[8];
#pragma unroll
        for (int j = 0; j < 8; ++j) {
            hu[j] = f2bf(wv[j]);
            float hif = __builtin_bit_cast(float, hu[j] << 16);
            lu[j] = f2bf(wv[j] - hif);
        }
        u32x4 ph = { hu[0] | (hu[1] << 16), hu[2] | (hu[3] << 16),
                     hu[4] | (hu[5] << 16), hu[6] | (hu[7] << 16) };
        u32x4 pl = { lu[0] | (lu[1] << 16), lu[2] | (lu[3] << 16),
                     lu[4] | (lu[5] << 16), lu[6] | (lu[7] << 16) };
        whi[cc] = __builtin_bit_cast(bf16x8, ph);
        wlo[cc] = __builtin_bit_cast(bf16x8, pl);
    }

    const float bhh = b_hh[blk * 16 + (ln & 15)];
    const int frag_k = w * 256 + (ln >> 4) * 8;

    for (int t = 0; t < T_SEQ; ++t) {
        // xproj prefetch (wave 0): cached, issued before the flag wait
        float xp[4];
        if (w == 0) {
            int colp = blk * 16 + (ln & 15);
            int bb = (ln >> 4) * 4;
#pragma unroll
            for (int r = 0; r < 4; ++r) {
                int b = (bb + r) & 7;
                xp[r] = xproj[(size_t)(t * NB + b) * HID + colp];
            }
        }

        f32x4 acc0 = {0.f, 0.f, 0.f, 0.f}, acc1 = {0.f, 0.f, 0.f, 0.f};
        if (t > 0) {
            // flag wait: lane ln polls prog[ln] (bypass, tiny); every wave polls
            {
                const unsigned int* pp = prog + ln;
                unsigned int v;
                do {
                    asm volatile("global_load_dword %0, %1, off sc0 sc1\n\t"
                                 "s_waitcnt vmcnt(0)"
                                 : "=v"(v) : "v"(pp) : "memory");
                } while (!__all(v >= (unsigned int)t));
            }
            // bulk h fragment load: plain CACHED (first touch after gate -> fresh;
            // co-XCD blocks share the L2 fill)
            const u32x4* hp4 = (const u32x4*)(hseq + (size_t)(t - 1) * 8192
                                              + (ln & 7) * 1024 + frag_k);
#pragma unroll
            for (int cc = 0; cc < 8; ++cc) {
                u32x4 qa = hp4[cc * 8];
                u32x4 qb = hp4[cc * 8 + 1];
                bf16x8 ah = mk_hi(qa, qb);
                bf16x8 al = mk_lo(qa, qb);
                if (cc & 1) {
                    acc1 = __builtin_amdgcn_mfma_f32_16x16x32_bf16(ah, whi[cc], acc1, 0, 0, 0);
                    acc1 = __builtin_amdgcn_mfma_f32_16x16x32_bf16(al, whi[cc], acc1, 0, 0, 0);
                    acc1 = __builtin_amdgcn_mfma_f32_16x16x32_bf16(ah, wlo[cc], acc1, 0, 0, 0);
                } else {
                    acc0 = __builtin_amdgcn_mfma_f32_16x16x32_bf16(ah, whi[cc], acc0, 0, 0, 0);
                    acc0 = __builtin_amdgcn_mfma_f32_16x16x32_bf16(al, whi[cc], acc0, 0, 0, 0);
                    acc0 = __builtin_amdgcn_mfma_f32_16x16x32_bf16(ah, wlo[cc], acc0, 0, 0, 0);
                }
            }
        }
        f32x4 asum = acc0 + acc1;
        *(f32x4*)&part[t & 1][w][ln][0] = asum;
        __syncthreads();

        if (w == 0) {
            f32x4 p0 = *(const f32x4*)&part[t & 1][0][ln][0];
            f32x4 p1 = *(const f32x4*)&part[t & 1][1][ln][0];
            f32x4 p2 = *(const f32x4*)&part[t & 1][2][ln][0];
            f32x4 p3 = *(const f32x4*)&part[t & 1][3][ln][0];
            f32x4 csum = (p0 + p1) + (p2 + p3);
            if (ln < 32) {
                int colp = blk * 16 + (ln & 15);
                int bb = (ln >> 4) * 4;
                unsigned int* slot_w = hseq + (size_t)t * 8192;
                uint32_t pk[4], hb[4];
#pragma unroll
                for (int r = 0; r < 4; ++r) {
                    float x = xp[r] + csum[r] + bhh;
                    float h = tanhf(x);
                    uint32_t hi = f2bf(h);
                    float hif = __builtin_bit_cast(float, hi << 16);
                    uint32_t lo = f2bf(h - hif);
                    pk[r] = (hi << 16) | lo;
                    hb[r] = hi;
                }
                // publish h data: write-through to the coherent point
#pragma unroll
                for (int r = 0; r < 4; ++r) {
                    unsigned int* ha = slot_w + (bb + r) * 1024 + colp;
                    asm volatile("global_store_dword %0, %1, off sc0 sc1"
                                 :: "v"(ha), "v"(pk[r]) : "memory");
                }
                // hs archive (plain cached; consumed by k_fc after kernel boundary)
#pragma unroll
                for (int r = 0; r < 4; ++r)
                    hs[(size_t)(t * NB + bb + r) * HID + colp] = (unsigned short)hb[r];
            }
            // release: drain data stores, then publish progress flag
            asm volatile("s_waitcnt vmcnt(0)" ::: "memory");
            if (ln == 0)
                (void)__hip_atomic_exchange(prog + blk, (unsigned int)(t + 1),
                                            __ATOMIC_RELAXED, __HIP_MEMORY_SCOPE_AGENT);
        }
    }
}

// ---------------- fc: C[m][n] = hs[m][:] . W_fc[n][:] + b_fc[n], bf16 MFMA ----------------
// grid dim3(16,250): bm fast -> the 16 consumers of each B-tile dispatch adjacently
__global__ void k_fc(const unsigned short* __restrict__ A,   // [2048][1024] bf16
                     const unsigned short* __restrict__ Bw,  // [32000][1024] bf16
                     const float* __restrict__ bias,
                     float* __restrict__ out) {              // [8][256][32000] f32
    __shared__ __align__(16) unsigned short As[128 * 32];
    __shared__ __align__(16) unsigned short Bs[128 * 32];
    const int tid = threadIdx.x;
    const int w = tid >> 6, ln = tid & 63;
    const int bm = blockIdx.x, bn = blockIdx.y;
    const int wm = (w >> 1) * 64, wn = (w & 1) * 64;
    const int srow = tid >> 2;
    const int scol = (tid & 3) * 8;
    const unsigned short* Ag = A  + (size_t)(bm * 128 + srow) * 1024 + scol;
    const unsigned short* Bg = Bw + (size_t)(bn * 128 + srow) * 1024 + scol;
    unsigned short* ldsA0 = As + w * 512;
    unsigned short* ldsA1 = As + 2048 + w * 512;
    unsigned short* ldsB0 = Bs + w * 512;
    unsigned short* ldsB1 = Bs + 2048 + w * 512;

    f32x4 acc[4][4] = {};
    const int fr = ln & 15;
    const int kq = (ln >> 4) * 8;

    for (int kk = 0; kk < 1024; kk += 32) {
        __syncthreads();
        __builtin_amdgcn_global_load_lds((const AS1 void*)(Ag + kk),             (AS3 void*)ldsA0, 16, 0, 0);
        __builtin_amdgcn_global_load_lds((const AS1 void*)(Ag + 64 * 1024 + kk), (AS3 void*)ldsA1, 16, 0, 0);
        __builtin_amdgcn_global_load_lds((const AS1 void*)(Bg + kk),             (AS3 void*)ldsB0, 16, 0, 0);
        __builtin_amdgcn_global_load_lds((const AS1 void*)(Bg + 64 * 1024 + kk), (AS3 void*)ldsB1, 16, 0, 0);
        __syncthreads();
        bf16x8 af[4], bf[4];
#pragma unroll
        for (int i = 0; i < 4; ++i)
            af[i] = *(const bf16x8*)&As[(wm + i * 16 + fr) * 32 + kq];
#pragma unroll
        for (int j = 0; j < 4; ++j)
            bf[j] = *(const bf16x8*)&Bs[(wn + j * 16 + fr) * 32 + kq];
#pragma unroll
        for (int i = 0; i < 4; ++i)
#pragma unroll
            for (int j = 0; j < 4; ++j)
                acc[i][j] = __builtin_amdgcn_mfma_f32_16x16x32_bf16(af[i], bf[j], acc[i][j], 0, 0, 0);
    }

    const int fq = ln >> 4;
#pragma unroll
    for (int i = 0; i < 4; ++i) {
#pragma unroll
        for (int j = 0; j < 4; ++j) {
            int n = bn * 128 + wn + j * 16 + fr;
            float bv = bias[n];
#pragma unroll
            for (int r = 0; r < 4; ++r) {
                int m = bm * 128 + wm + i * 16 + fq * 4 + r;
                int t = m >> 3, b = m & 7;
                out[(size_t)b * T_SEQ * NOUT + (size_t)t * NOUT + n] = acc[i][j][r] + bv;
            }
        }
    }
}

extern "C" void kernel_launch(void* const* d_in, const int* in_sizes, int n_in,
                              void* d_out, int out_size, void* d_ws, size_t ws_size,
                              hipStream_t stream) {
    const int*   inputs = (const int*)d_in[0];
    const float* embed  = (const float*)d_in[1];
    const float* W_ih   = (const float*)d_in[2];
    const float* W_hh   = (const float*)d_in[3];
    const float* b_ih   = (const float*)d_in[4];
    const float* b_hh   = (const float*)d_in[5];
    const float* W_fc   = (const float*)d_in[6];
    const float* b_fc   = (const float*)d_in[7];
    float* out = (float*)d_out;

    char* ws = (char*)d_ws;
    unsigned int*   prog  = (unsigned int*)(ws);                        // 256 B (pad 512)
    unsigned int*   hseq  = (unsigned int*)(ws + 512);                  // 256*8192*4 = 8 MB
    float*          xproj = (float*)(ws + 512 + 8388608);               // 8 MB
    unsigned short* hs    = (unsigned short*)(ws + 512 + 8388608 + 8388608);        // 4 MB
    unsigned short* wfcb  = (unsigned short*)(ws + 512 + 8388608 + 8388608 + 4194304); // 64 MB

    hipMemsetAsync(prog, 0, 512, stream);
    k_convert_wfc<<<2048, 256, 0, stream>>>(W_fc, wfcb);
    k_xproj<<<dim3(16, 32), 256, 0, stream>>>(inputs, embed, W_ih, b_ih, xproj);
    k_rnn<<<RBLK, 256, 0, stream>>>(W_hh, b_hh, xproj, hseq, hs, prog);
    k_fc<<<dim3(16, 250), 256, 0, stream>>>(hs, wfcb, b_fc, out);
}